// Round 6
// baseline (624.818 us; speedup 1.0000x reference)
//
#include <hip/hip_runtime.h>
#include <math.h>

// Problem: N=8, C=1, H=W=512 fp32. 16 images (8 sigmoid + 8 target) skeletonized.
#define IMG   512
#define NSAMP 8
#define NIMG  16
#define PS    (IMG * IMG)

#define NBANDS 32
#define BH     (IMG / NBANDS)   // 16  (R0 = band*16 is always even -> static parities)

__device__ __forceinline__ float sigm(float x) { return 1.0f / (1.0f + expf(-x)); }

// cross-lane shift by 1 at VALU rate (DPP). Stencils are L/R symmetric, so the
// direction ambiguity is harmless. Shifted-in lanes -> 0; garbage stays in the
// (C+1)-lane column halo.
__device__ __forceinline__ float dpp_a(float x) {
#if __has_builtin(__builtin_amdgcn_update_dpp)
    return __int_as_float(__builtin_amdgcn_update_dpp(0, __float_as_int(x),
                                                      0x130, 0xF, 0xF, true)); // WAVE_SHL1
#else
    return __shfl_down(x, 1, 64);
#endif
}
__device__ __forceinline__ float dpp_b(float x) {
#if __has_builtin(__builtin_amdgcn_update_dpp)
    return __int_as_float(__builtin_amdgcn_update_dpp(0, __float_as_int(x),
                                                      0x138, 0xF, 0xF, true)); // WAVE_SHR1
#else
    return __shfl_up(x, 1, 64);
#endif
}

// ---- prep: X[0:n]=sigmoid(logits), X[n:2n]=target (S untouched: first fused
// launch is INIT and neither reads nor needs zeroed S) ----
__global__ __launch_bounds__(256) void prep_kernel(const float4* __restrict__ lg,
                                                   const float4* __restrict__ tg,
                                                   float4* __restrict__ X, int n4)
{
    int i = blockIdx.x * 256 + threadIdx.x;
    if (i < n4) {
        float4 L = lg[i];
        X[i]      = make_float4(sigm(L.x), sigm(L.y), sigm(L.z), sigm(L.w));
        X[i + n4] = tg[i];
    }
}

// ---- register line-pipeline, 1 row/step, C fused levels, no LDS ----
// Level l at step t: e = x_{l+1}[t-l-1] = cross-erode(x_l); hm = rowmax3(e);
// dil(row t-l-2) = max(hm[t-l-3], hm[t-l-2], hm[t-l-1]); d = relu(x_l[t-l-2]-dil);
// skel row t-l-2 updated: s' = s + d - s*d (== s + relu(d - s*d); exact since
// d>=0, s<=1 and rounding is monotone).
// All rotating state is indexed by compile-time parities/modulos under an
// INNER=2C (or C if even) unroll, so rotations cost zero moves.
template<int C, bool ER, bool EC, bool INIT, bool LAST>
__device__ __forceinline__ void pipe_run(const float* __restrict__ xg,
                                         float* __restrict__ xo,
                                         float* __restrict__ Sg,
                                         int R0, int gcol, bool colOK, bool owned)
{
    const float INF = __builtin_inff();
    constexpr int RAW    = BH + 2 * C + 2;
    constexpr int INNER  = (C % 2 == 0) ? C : 2 * C;
    constexpr int NSTEPS = ((RAW + INNER - 1) / INNER) * INNER;
    constexpr int PAD    = NSTEPS - RAW;
    constexpr int T0PAR  = (C + 1 + PAD) & 1;     // parity of t0 (R0 even)
    constexpr int XS0    = 2 * C + 1 + PAD;       // k-window start for x stores
    constexpr int SS0    = 2 * C + 2 + PAD;       // k-window start for skel stores
    const int t0 = R0 - C - 1 - PAD;

    float W[C][2], HM[C][2], SK[C], XQ[C], SQ[C];
    #pragma unroll
    for (int l = 0; l < C; ++l) {
        W[l][0] = INF;  W[l][1] = INF;
        HM[l][0] = -INF; HM[l][1] = -INF;
        SK[l] = 0.f;
    }

    const float* xp = xg + gcol;
    float* sp = Sg + gcol;
    float* op = xo + gcol;

    auto xld = [&](int r) -> float {
        if (ER || EC) {
            bool ok = (!ER || (unsigned)r < (unsigned)IMG) && (!EC || colOK);
            float v = INF;
            if (ok) v = xp[r * IMG];
            return v;
        }
        return xp[r * IMG];          // interior: provably in-bounds
    };
    auto sld = [&](int r) -> float {
        if (INIT) return 0.f;
        if (ER || EC) {
            bool ok = (!ER || (unsigned)r < (unsigned)IMG) && (!EC || colOK);
            float v = 0.f;
            if (ok) v = sp[r * IMG];
            return v;
        }
        return sp[r * IMG];
    };

    #pragma unroll
    for (int i = 0; i < C; ++i) XQ[i] = xld(t0 + i);
    #pragma unroll
    for (int i = 0; i < C; ++i) SQ[i] = INIT ? 0.f : sld(t0 - 1 + i);

    for (int kk = 0; kk < NSTEPS; kk += INNER) {       // rolled outer loop
        #pragma unroll
        for (int j = 0; j < INNER; ++j) {              // fully unrolled: j static
            const int k = kk + j;
            const int t = t0 + k;
            const int qi = j % C;                      // static
            float Cin = XQ[qi];                        // x_0 row t
            XQ[qi] = xld(t + C);                       // prefetch depth C
            float snew = SQ[qi];                       // s row t-1
            if (!INIT) SQ[qi] = sld(t + C - 1);

            #pragma unroll
            for (int l = 0; l < C; ++l) {
                const int bp = (T0PAR + j + l + 1) & 1;  // parity of row t-l-1
                float Acur = W[l][bp ^ 1];               // x_l row t-l-2
                float Bcur = W[l][bp];                   // x_l row t-l-1
                float e = fminf(fminf(Acur, Cin), Bcur);
                e = fminf(e, dpp_a(Bcur));
                e = fminf(e, dpp_b(Bcur));
                if (ER) e = ((unsigned)(t - l - 1) < (unsigned)IMG) ? e : INF;
                float xd = e;
                if (EC) { xd = colOK ? e : -INF; e = colOK ? e : INF; }
                float hm = fmaxf(xd, fmaxf(dpp_a(xd), dpp_b(xd)));
                if (ER) hm = ((unsigned)(t - l - 1) < (unsigned)IMG) ? hm : -INF;
                // HM[l][bp] holds hm row t-l-3 (old HMA), HM[l][bp^1] row t-l-2
                float dil = fmaxf(fmaxf(HM[l][bp], HM[l][bp ^ 1]), hm);
                float d = fmaxf(Acur - dil, 0.f);
                const int si = (l + C - qi) % C;         // SK slot of stage l (static)
                float skl = SK[si];
                SK[si] = (skl + d) - skl * d;
                W[l][bp ^ 1] = Cin;                      // row t-l overwrites row t-l-2
                HM[l][bp] = hm;                          // row t-l-1 overwrites t-l-3
                Cin = e;                                 // feed next level
            }

            // stores: x_C row t-C, skel row t-C-1 (wave-uniform k-guards)
            if (!LAST) {
                if ((unsigned)(k - XS0) < BH) { if (owned) op[(t - C) * IMG] = Cin; }
            }
            if ((unsigned)(k - SS0) < BH) {
                const int so = (2 * C - 1 - qi) % C;     // stage C-1 slot (static)
                if (owned) sp[(t - C - 1) * IMG] = SK[so];
            }
            // insert s[t-1] at next step's stage-0 slot (== retiring stage C-1 slot)
            SK[(C - ((j + 1) % C)) % C] = snew;
        }
    }
}

template<int C, bool INIT, bool LAST>
__global__ __launch_bounds__(256, 5) void fused_pipe(const float* __restrict__ xin,
                                                     float* __restrict__ xout,
                                                     float* __restrict__ S)
{
    constexpr int OW = 64 - 2 * (C + 1);                 // owned cols per wave
    constexpr int NSTRIP = (IMG + OW - 1) / OW;          // 10 (C=5), 11 (C=6)
    const int lane = threadIdx.x & 63;
    const int task = blockIdx.x * 4 + (threadIdx.x >> 6);
    const int strip = task % NSTRIP;
    const int rem = task / NSTRIP;
    const int band = rem % NBANDS;
    const int img = rem / NBANDS;
    const int R0 = band * BH;
    const int gcol = strip * OW - (C + 1) + lane;
    const bool colOK = (unsigned)gcol < (unsigned)IMG;
    const bool owned = (lane >= C + 1) && (lane < C + 1 + OW) && colOK;
    const float* xg = xin + (size_t)img * PS;
    float* xo = xout + (size_t)img * PS;
    float* Sg = S + (size_t)img * PS;
    const bool erow = (band == 0) || (band == NBANDS - 1);
    const bool ecol = (strip == 0) || (strip * OW - (C + 1) + 63 >= IMG);

    if (erow) {
        if (ecol) pipe_run<C, true , true , INIT, LAST>(xg, xo, Sg, R0, gcol, colOK, owned);
        else      pipe_run<C, true , false, INIT, LAST>(xg, xo, Sg, R0, gcol, colOK, owned);
    } else {
        if (ecol) pipe_run<C, false, true , INIT, LAST>(xg, xo, Sg, R0, gcol, colOK, owned);
        else      pipe_run<C, false, false, INIT, LAST>(xg, xo, Sg, R0, gcol, colOK, owned);
    }
}

// ---- reduction: per-block partials, no global atomics ----
__global__ __launch_bounds__(256) void reduce_kernel(const float* __restrict__ logits,
                                                     const float* __restrict__ target,
                                                     const float* __restrict__ S,
                                                     float* __restrict__ partial)
{
    const int sample = blockIdx.y;
    const size_t base = (size_t)sample * PS;
    const float4* p4  = (const float4*)(logits + base);
    const float4* t4  = (const float4*)(target + base);
    const float4* sp4 = (const float4*)(S + base);
    const float4* sl4 = (const float4*)(S + (size_t)NSAMP * PS + base);
    float v[7] = {0.f, 0.f, 0.f, 0.f, 0.f, 0.f, 0.f};
    const int n4 = PS / 4;
    for (int i = blockIdx.x * 256 + threadIdx.x; i < n4; i += 32 * 256) {
        float4 L = p4[i], Tt = t4[i], SP = sp4[i], SL = sl4[i];
        float p;
        p = sigm(L.x); v[0] += SP.x * Tt.x; v[1] += SP.x; v[2] += SL.x * p; v[3] += SL.x; v[4] += p * Tt.x; v[5] += p; v[6] += Tt.x;
        p = sigm(L.y); v[0] += SP.y * Tt.y; v[1] += SP.y; v[2] += SL.y * p; v[3] += SL.y; v[4] += p * Tt.y; v[5] += p; v[6] += Tt.y;
        p = sigm(L.z); v[0] += SP.z * Tt.z; v[1] += SP.z; v[2] += SL.z * p; v[3] += SL.z; v[4] += p * Tt.z; v[5] += p; v[6] += Tt.z;
        p = sigm(L.w); v[0] += SP.w * Tt.w; v[1] += SP.w; v[2] += SL.w * p; v[3] += SL.w; v[4] += p * Tt.w; v[5] += p; v[6] += Tt.w;
    }
    #pragma unroll
    for (int off = 32; off > 0; off >>= 1)
        #pragma unroll
        for (int q = 0; q < 7; ++q) v[q] += __shfl_down(v[q], off);
    __shared__ float wred[4][7];
    int lane = threadIdx.x & 63, w = threadIdx.x >> 6;
    if (lane == 0)
        #pragma unroll
        for (int q = 0; q < 7; ++q) wred[w][q] = v[q];
    __syncthreads();
    if (threadIdx.x == 0) {
        #pragma unroll
        for (int q = 0; q < 7; ++q)
            partial[(sample * 32 + blockIdx.x) * 7 + q] =
                wred[0][q] + wred[1][q] + wred[2][q] + wred[3][q];
    }
}

__global__ __launch_bounds__(256) void final_kernel(const float* __restrict__ partial,
                                                    float* __restrict__ out)
{
    const int t = threadIdx.x;
    const int sample = t >> 5, part = t & 31;
    float v[7];
    #pragma unroll
    for (int q = 0; q < 7; ++q) v[q] = partial[(sample * 32 + part) * 7 + q];
    #pragma unroll
    for (int off = 16; off > 0; off >>= 1)
        #pragma unroll
        for (int q = 0; q < 7; ++q) v[q] += __shfl_down(v[q], off, 32);
    __shared__ float acc[NSAMP][7];
    if (part == 0)
        #pragma unroll
        for (int q = 0; q < 7; ++q) acc[sample][q] = v[q];
    __syncthreads();
    if (t == 0) {
        float cl = 0.f, dice = 0.f;
        for (int n = 0; n < NSAMP; n++) {
            float A = acc[n][0], Bv = acc[n][1], Cc = acc[n][2], D = acc[n][3];
            float E = acc[n][4], F = acc[n][5], G = acc[n][6];
            float tprec = (A + 1.0f) / (Bv + 1.0f);
            float tsens = (Cc + 1.0f) / (D + 1.0f);
            cl   += 1.0f - 2.0f * tprec * tsens / (tprec + tsens);
            dice += 1.0f - 2.0f * (E + 1.0f) / (F + G + 1.0f);
        }
        out[0] = 0.7f * (dice / NSAMP) + 0.3f * (cl / NSAMP);
    }
}

extern "C" void kernel_launch(void* const* d_in, const int* in_sizes, int n_in,
                              void* d_out, int out_size, void* d_ws, size_t ws_size,
                              hipStream_t stream)
{
    const float* logits = (const float*)d_in[0];
    const float* target = (const float*)d_in[1];
    float* out = (float*)d_out;

    const size_t NTOT = (size_t)NIMG * PS;
    float* Xa = (float*)d_ws;                       // Xa | Xb | S | partial
    float* Xb = Xa + NTOT;
    float* S  = Xb + NTOT;
    float* partial = S + NTOT;                      // 256*7 floats

    const int n4 = (NSAMP * PS) / 4;
    prep_kernel<<<n4 / 256, 256, 0, stream>>>((const float4*)logits, (const float4*)target,
                                              (float4*)Xa, n4);

    // 51 levels = 6 (INIT) + 9*5.  blocks = NSTRIP*NBANDS*NIMG/4.
    const int B6 = 11 * NBANDS * NIMG / 4;          // 1408 blocks (5632 waves)
    const int B5 = 10 * NBANDS * NIMG / 4;          // 1280 blocks (5120 waves)
    fused_pipe<6, true , false><<<B6, 256, 0, stream>>>(Xa, Xb, S);
    fused_pipe<5, false, false><<<B5, 256, 0, stream>>>(Xb, Xa, S);
    fused_pipe<5, false, false><<<B5, 256, 0, stream>>>(Xa, Xb, S);
    fused_pipe<5, false, false><<<B5, 256, 0, stream>>>(Xb, Xa, S);
    fused_pipe<5, false, false><<<B5, 256, 0, stream>>>(Xa, Xb, S);
    fused_pipe<5, false, false><<<B5, 256, 0, stream>>>(Xb, Xa, S);
    fused_pipe<5, false, false><<<B5, 256, 0, stream>>>(Xa, Xb, S);
    fused_pipe<5, false, false><<<B5, 256, 0, stream>>>(Xb, Xa, S);
    fused_pipe<5, false, false><<<B5, 256, 0, stream>>>(Xa, Xb, S);
    fused_pipe<5, false, true ><<<B5, 256, 0, stream>>>(Xb, Xa, S);   // last: skip dead x-write

    reduce_kernel<<<dim3(32, NSAMP), 256, 0, stream>>>(logits, target, S, partial);
    final_kernel<<<1, 256, 0, stream>>>(partial, out);
}

// Round 7
// 324.635 us; speedup vs baseline: 1.9247x; 1.9247x over previous
//
#include <hip/hip_runtime.h>
#include <math.h>

// Problem: N=8, C=1, H=W=512 fp32. 16 images (8 sigmoid + 8 target) skeletonized.
#define IMG   512
#define NSAMP 8
#define NIMG  16
#define PS    (IMG * IMG)

#define NBANDS 16
#define BH     (IMG / NBANDS)   // 32  (R0 = band*32 always even -> static parities)

__device__ __forceinline__ float sigm(float x) { return 1.0f / (1.0f + expf(-x)); }

// cross-lane shift by 1 at VALU rate (DPP). Stencils are L/R symmetric, so the
// direction ambiguity is harmless. Shifted-in lanes -> 0; garbage stays in the
// (C+1)-lane column halo.
__device__ __forceinline__ float dpp_a(float x) {
#if __has_builtin(__builtin_amdgcn_update_dpp)
    return __int_as_float(__builtin_amdgcn_update_dpp(0, __float_as_int(x),
                                                      0x130, 0xF, 0xF, true)); // WAVE_SHL1
#else
    return __shfl_down(x, 1, 64);
#endif
}
__device__ __forceinline__ float dpp_b(float x) {
#if __has_builtin(__builtin_amdgcn_update_dpp)
    return __int_as_float(__builtin_amdgcn_update_dpp(0, __float_as_int(x),
                                                      0x138, 0xF, 0xF, true)); // WAVE_SHR1
#else
    return __shfl_up(x, 1, 64);
#endif
}

// ---- prep: X[0:n]=sigmoid(logits), X[n:2n]=target (S untouched: first fused
// launch is INIT and neither reads nor needs zeroed S) ----
__global__ __launch_bounds__(256) void prep_kernel(const float4* __restrict__ lg,
                                                   const float4* __restrict__ tg,
                                                   float4* __restrict__ X, int n4)
{
    int i = blockIdx.x * 256 + threadIdx.x;
    if (i < n4) {
        float4 L = lg[i];
        X[i]      = make_float4(sigm(L.x), sigm(L.y), sigm(L.z), sigm(L.w));
        X[i + n4] = tg[i];
    }
}

// ---- register line-pipeline, 1 row/step, C fused levels, no LDS ----
// Level l at step t: e = x_{l+1}[t-l-1] = cross-erode(x_l); hm = rowmax3(e);
// dil(row t-l-2) = max(hm[t-l-3], hm[t-l-2], hm[t-l-1]); d = relu(x_l[t-l-2]-dil);
// skel row t-l-2: s' = s + d - s*d (== s + relu(d - s*d); exact since d>=0, s<=1).
// All rotating state is indexed by compile-time parities/modulos under an
// INNER unroll (INNER = C even, 2C odd), so rotations cost zero moves.
// NOTE (R6 post-mortem): do NOT cap occupancy via __launch_bounds__ second arg —
// it forced VGPR=48 and ~124 MB/launch of scratch-spill traffic (WRITE_SIZE 5x).
template<int C, bool ER, bool EC, bool INIT, bool LAST>
__device__ __forceinline__ void pipe_run(const float* __restrict__ xg,
                                         float* __restrict__ xo,
                                         float* __restrict__ Sg,
                                         int R0, int gcol, bool colOK, bool owned)
{
    const float INF = __builtin_inff();
    constexpr int RAW    = BH + 2 * C + 2;
    constexpr int INNER  = (C % 2 == 0) ? C : 2 * C;
    constexpr int NSTEPS = ((RAW + INNER - 1) / INNER) * INNER;
    constexpr int PAD    = NSTEPS - RAW;
    constexpr int T0PAR  = (C + 1 + PAD) & 1;     // parity of t0 (R0 even)
    constexpr int XS0    = 2 * C + 1 + PAD;       // k-window start for x stores
    constexpr int SS0    = 2 * C + 2 + PAD;       // k-window start for skel stores
    const int t0 = R0 - C - 1 - PAD;

    float W[C][2], HM[C][2], SK[C], XQ[C], SQ[C];
    #pragma unroll
    for (int l = 0; l < C; ++l) {
        W[l][0] = INF;  W[l][1] = INF;
        HM[l][0] = -INF; HM[l][1] = -INF;
        SK[l] = 0.f;
    }

    const float* xp = xg + gcol;
    float* sp = Sg + gcol;
    float* op = xo + gcol;

    auto xld = [&](int r) -> float {
        if (ER || EC) {
            bool ok = (!ER || (unsigned)r < (unsigned)IMG) && (!EC || colOK);
            float v = INF;
            if (ok) v = xp[r * IMG];
            return v;
        }
        return xp[r * IMG];          // interior: provably in-bounds
    };
    auto sld = [&](int r) -> float {
        if (INIT) return 0.f;
        if (ER || EC) {
            bool ok = (!ER || (unsigned)r < (unsigned)IMG) && (!EC || colOK);
            float v = 0.f;
            if (ok) v = sp[r * IMG];
            return v;
        }
        return sp[r * IMG];
    };

    #pragma unroll
    for (int i = 0; i < C; ++i) XQ[i] = xld(t0 + i);
    #pragma unroll
    for (int i = 0; i < C; ++i) SQ[i] = INIT ? 0.f : sld(t0 - 1 + i);

    for (int kk = 0; kk < NSTEPS; kk += INNER) {       // rolled outer loop
        #pragma unroll
        for (int j = 0; j < INNER; ++j) {              // fully unrolled: j static
            const int k = kk + j;
            const int t = t0 + k;
            const int qi = j % C;                      // static
            float Cin = XQ[qi];                        // x_0 row t
            XQ[qi] = xld(t + C);                       // prefetch depth C
            float snew = SQ[qi];                       // s row t-1
            if (!INIT) SQ[qi] = sld(t + C - 1);

            #pragma unroll
            for (int l = 0; l < C; ++l) {
                const int bp = (T0PAR + j + l + 1) & 1;  // parity of row t-l-1
                float Acur = W[l][bp ^ 1];               // x_l row t-l-2
                float Bcur = W[l][bp];                   // x_l row t-l-1
                float e = fminf(fminf(Acur, Cin), Bcur);
                e = fminf(e, dpp_a(Bcur));
                e = fminf(e, dpp_b(Bcur));
                if (ER) e = ((unsigned)(t - l - 1) < (unsigned)IMG) ? e : INF;
                float xd = e;
                if (EC) { xd = colOK ? e : -INF; e = colOK ? e : INF; }
                float hm = fmaxf(xd, fmaxf(dpp_a(xd), dpp_b(xd)));
                if (ER) hm = ((unsigned)(t - l - 1) < (unsigned)IMG) ? hm : -INF;
                // HM[l][bp] holds hm row t-l-3 (old HMA), HM[l][bp^1] row t-l-2
                float dil = fmaxf(fmaxf(HM[l][bp], HM[l][bp ^ 1]), hm);
                float d = fmaxf(Acur - dil, 0.f);
                const int si = (l + C - qi) % C;         // SK slot of stage l (static)
                float skl = SK[si];
                SK[si] = (skl + d) - skl * d;
                W[l][bp ^ 1] = Cin;                      // row t-l overwrites row t-l-2
                HM[l][bp] = hm;                          // row t-l-1 overwrites t-l-3
                Cin = e;                                 // feed next level
            }

            // stores: x_C row t-C, skel row t-C-1 (wave-uniform k-guards)
            if (!LAST) {
                if ((unsigned)(k - XS0) < BH) { if (owned) op[(t - C) * IMG] = Cin; }
            }
            if ((unsigned)(k - SS0) < BH) {
                const int so = (2 * C - 1 - qi) % C;     // stage C-1 slot (static)
                if (owned) sp[(t - C - 1) * IMG] = SK[so];
            }
            // insert s[t-1] at next step's stage-0 slot (== retiring stage C-1 slot)
            SK[(C - ((j + 1) % C)) % C] = snew;
        }
    }
}

template<int C, bool INIT, bool LAST>
__global__ __launch_bounds__(256) void fused_pipe(const float* __restrict__ xin,
                                                  float* __restrict__ xout,
                                                  float* __restrict__ S)
{
    constexpr int OW = 64 - 2 * (C + 1);                 // owned cols per wave
    constexpr int NSTRIP = (IMG + OW - 1) / OW;          // 11 (C=6), 10 (C=3)
    const int lane = threadIdx.x & 63;
    const int task = blockIdx.x * 4 + (threadIdx.x >> 6);
    const int strip = task % NSTRIP;
    const int rem = task / NSTRIP;
    const int band = rem % NBANDS;
    const int img = rem / NBANDS;
    const int R0 = band * BH;
    const int gcol = strip * OW - (C + 1) + lane;
    const bool colOK = (unsigned)gcol < (unsigned)IMG;
    const bool owned = (lane >= C + 1) && (lane < C + 1 + OW) && colOK;
    const float* xg = xin + (size_t)img * PS;
    float* xo = xout + (size_t)img * PS;
    float* Sg = S + (size_t)img * PS;
    const bool erow = (band == 0) || (band == NBANDS - 1);
    const bool ecol = (strip == 0) || (strip * OW - (C + 1) + 63 >= IMG);

    if (erow) {
        if (ecol) pipe_run<C, true , true , INIT, LAST>(xg, xo, Sg, R0, gcol, colOK, owned);
        else      pipe_run<C, true , false, INIT, LAST>(xg, xo, Sg, R0, gcol, colOK, owned);
    } else {
        if (ecol) pipe_run<C, false, true , INIT, LAST>(xg, xo, Sg, R0, gcol, colOK, owned);
        else      pipe_run<C, false, false, INIT, LAST>(xg, xo, Sg, R0, gcol, colOK, owned);
    }
}

// ---- reduction: per-block partials, no global atomics ----
__global__ __launch_bounds__(256) void reduce_kernel(const float* __restrict__ logits,
                                                     const float* __restrict__ target,
                                                     const float* __restrict__ S,
                                                     float* __restrict__ partial)
{
    const int sample = blockIdx.y;
    const size_t base = (size_t)sample * PS;
    const float4* p4  = (const float4*)(logits + base);
    const float4* t4  = (const float4*)(target + base);
    const float4* sp4 = (const float4*)(S + base);
    const float4* sl4 = (const float4*)(S + (size_t)NSAMP * PS + base);
    float v[7] = {0.f, 0.f, 0.f, 0.f, 0.f, 0.f, 0.f};
    const int n4 = PS / 4;
    for (int i = blockIdx.x * 256 + threadIdx.x; i < n4; i += 32 * 256) {
        float4 L = p4[i], Tt = t4[i], SP = sp4[i], SL = sl4[i];
        float p;
        p = sigm(L.x); v[0] += SP.x * Tt.x; v[1] += SP.x; v[2] += SL.x * p; v[3] += SL.x; v[4] += p * Tt.x; v[5] += p; v[6] += Tt.x;
        p = sigm(L.y); v[0] += SP.y * Tt.y; v[1] += SP.y; v[2] += SL.y * p; v[3] += SL.y; v[4] += p * Tt.y; v[5] += p; v[6] += Tt.y;
        p = sigm(L.z); v[0] += SP.z * Tt.z; v[1] += SP.z; v[2] += SL.z * p; v[3] += SL.z; v[4] += p * Tt.z; v[5] += p; v[6] += Tt.z;
        p = sigm(L.w); v[0] += SP.w * Tt.w; v[1] += SP.w; v[2] += SL.w * p; v[3] += SL.w; v[4] += p * Tt.w; v[5] += p; v[6] += Tt.w;
    }
    #pragma unroll
    for (int off = 32; off > 0; off >>= 1)
        #pragma unroll
        for (int q = 0; q < 7; ++q) v[q] += __shfl_down(v[q], off);
    __shared__ float wred[4][7];
    int lane = threadIdx.x & 63, w = threadIdx.x >> 6;
    if (lane == 0)
        #pragma unroll
        for (int q = 0; q < 7; ++q) wred[w][q] = v[q];
    __syncthreads();
    if (threadIdx.x == 0) {
        #pragma unroll
        for (int q = 0; q < 7; ++q)
            partial[(sample * 32 + blockIdx.x) * 7 + q] =
                wred[0][q] + wred[1][q] + wred[2][q] + wred[3][q];
    }
}

__global__ __launch_bounds__(256) void final_kernel(const float* __restrict__ partial,
                                                    float* __restrict__ out)
{
    const int t = threadIdx.x;
    const int sample = t >> 5, part = t & 31;
    float v[7];
    #pragma unroll
    for (int q = 0; q < 7; ++q) v[q] = partial[(sample * 32 + part) * 7 + q];
    #pragma unroll
    for (int off = 16; off > 0; off >>= 1)
        #pragma unroll
        for (int q = 0; q < 7; ++q) v[q] += __shfl_down(v[q], off, 32);
    __shared__ float acc[NSAMP][7];
    if (part == 0)
        #pragma unroll
        for (int q = 0; q < 7; ++q) acc[sample][q] = v[q];
    __syncthreads();
    if (t == 0) {
        float cl = 0.f, dice = 0.f;
        for (int n = 0; n < NSAMP; n++) {
            float A = acc[n][0], Bv = acc[n][1], Cc = acc[n][2], D = acc[n][3];
            float E = acc[n][4], F = acc[n][5], G = acc[n][6];
            float tprec = (A + 1.0f) / (Bv + 1.0f);
            float tsens = (Cc + 1.0f) / (D + 1.0f);
            cl   += 1.0f - 2.0f * tprec * tsens / (tprec + tsens);
            dice += 1.0f - 2.0f * (E + 1.0f) / (F + G + 1.0f);
        }
        out[0] = 0.7f * (dice / NSAMP) + 0.3f * (cl / NSAMP);
    }
}

extern "C" void kernel_launch(void* const* d_in, const int* in_sizes, int n_in,
                              void* d_out, int out_size, void* d_ws, size_t ws_size,
                              hipStream_t stream)
{
    const float* logits = (const float*)d_in[0];
    const float* target = (const float*)d_in[1];
    float* out = (float*)d_out;

    const size_t NTOT = (size_t)NIMG * PS;
    float* Xa = (float*)d_ws;                       // Xa | Xb | S | partial
    float* Xb = Xa + NTOT;
    float* S  = Xb + NTOT;
    float* partial = S + NTOT;                      // 256*7 floats

    const int n4 = (NSAMP * PS) / 4;
    prep_kernel<<<n4 / 256, 256, 0, stream>>>((const float4*)logits, (const float4*)target,
                                              (float4*)Xa, n4);

    // 51 levels = 6 (INIT) + 7*6 + 3 (LAST).  blocks = NSTRIP*NBANDS*NIMG/4.
    const int B6 = 11 * NBANDS * NIMG / 4;          // 704 blocks (2816 waves)
    const int B3 = 10 * NBANDS * NIMG / 4;          // 640 blocks (2560 waves)
    fused_pipe<6, true , false><<<B6, 256, 0, stream>>>(Xa, Xb, S);
    fused_pipe<6, false, false><<<B6, 256, 0, stream>>>(Xb, Xa, S);
    fused_pipe<6, false, false><<<B6, 256, 0, stream>>>(Xa, Xb, S);
    fused_pipe<6, false, false><<<B6, 256, 0, stream>>>(Xb, Xa, S);
    fused_pipe<6, false, false><<<B6, 256, 0, stream>>>(Xa, Xb, S);
    fused_pipe<6, false, false><<<B6, 256, 0, stream>>>(Xb, Xa, S);
    fused_pipe<6, false, false><<<B6, 256, 0, stream>>>(Xa, Xb, S);
    fused_pipe<6, false, false><<<B6, 256, 0, stream>>>(Xb, Xa, S);
    fused_pipe<3, false, true ><<<B3, 256, 0, stream>>>(Xa, Xb, S);   // last: skip dead x-write

    reduce_kernel<<<dim3(32, NSAMP), 256, 0, stream>>>(logits, target, S, partial);
    final_kernel<<<1, 256, 0, stream>>>(partial, out);
}